// Round 3
// baseline (61.687 us; speedup 1.0000x reference)
//
#include <hip/hip_runtime.h>
#include <math.h>

// Problem constants
#define TT 64
#define NN 32
#define CC 128
#define DD 64

// ---------------------------------------------------------------------------
// DPP helpers: linear wave reduce-to-lane63 (VALU pipe, no DS traffic)
// ---------------------------------------------------------------------------
#define DPPADD(x, ctrl, rm)                                                   \
    x += __builtin_bit_cast(float, __builtin_amdgcn_update_dpp(               \
             0, __builtin_bit_cast(int, x), ctrl, rm, 0xf, false))

__device__ __forceinline__ float wave_reduce63(float x) {
    DPPADD(x, 0x111, 0xf);  // row_shr:1
    DPPADD(x, 0x112, 0xf);  // row_shr:2
    DPPADD(x, 0x114, 0xf);  // row_shr:4
    DPPADD(x, 0x118, 0xf);  // row_shr:8
    DPPADD(x, 0x142, 0xa);  // row_bcast:15
    DPPADD(x, 0x143, 0xc);  // row_bcast:31 -> lane63 = total
    return x;
}

__device__ __forceinline__ float rdlane(float x, int l) {
    return __builtin_bit_cast(float,
        __builtin_amdgcn_readlane(__builtin_bit_cast(int, x), l));
}

// ---------------------------------------------------------------------------
// Kernel 1a: one wave per (n,c). lane = jeffress dim d.
// No per-step cross-lane math: ballot the LIF spikes into a uniform mask,
// capture row t on lane t; post-loop lane t computes zc[t] locally, then a
// lane-redundant serial integrator-IF scan produces the spike mask.
// ---------------------------------------------------------------------------
__global__ __launch_bounds__(256) void k1a_jeffress(
    const float* __restrict__ x,                 // (T,N,2,C)
    unsigned long long* __restrict__ simask)     // (N*C)
{
#pragma clang fp contract(off)
    const int lane = threadIdx.x & 63;
    const int wid  = (blockIdx.x << 2) + (threadIdx.x >> 6);  // n*C + c
    const int n = wid >> 7;
    const int c = wid & 127;

    // lane t holds x0[t], x1[t]; pre-shifted delay-line bitmasks
    const float x0 = x[((lane * NN + n) * 2 + 0) * CC + c];
    const float x1 = x[((lane * NN + n) * 2 + 1) * CC + c];
    unsigned long long msh0 = __ballot(x0 > 0.5f) << lane;
    unsigned long long msh1 = __ballot(x1 > 0.5f) << (63 - lane);

    int ad = lane - (DD / 2);
    if (ad < 0) ad = -ad;
    if (ad == 0) ad = 1;                         // center clamp
    const float kint = 1.0f / (1.0f - expf(-(float)ad * 0.5f));

    // ---- LIF loop: no cross-lane dependencies per step ----
    float vj = 0.f;
    unsigned mylo = 0u, myhi = 0u;               // spike-matrix row t (on lane t)
#pragma unroll
    for (int t = 0; t < TT; ++t) {
        const float u = (float)((int)(msh0 & 1ull) + (int)(msh1 & 1ull));
        msh0 >>= 1; msh1 >>= 1;

        vj = vj + (u - vj) / 20.0f;              // precise div (bit-exact)
        const float sj = vj >= 1.0f ? 1.0f : 0.0f;
        vj *= (1.0f - sj);

        const unsigned long long m = __ballot(sj > 0.5f);
        if (t == lane) { mylo = (unsigned)m; myhi = (unsigned)(m >> 32); }
    }

    // ---- zc[t] on lane t: dot(spike row, kint) ----
    float zc = 0.f;
#pragma unroll
    for (int d = 0; d < 64; ++d) {
        const float kd = rdlane(kint, d);
        const unsigned bit = (d < 32) ? ((mylo >> d) & 1u)
                                      : ((myhi >> (d - 32)) & 1u);
        zc += kd * (float)bit;
    }

    // ---- serial integrator IF (lane-redundant, uniform) ----
    float vi = 0.f, sreg = 0.f;
#pragma unroll
    for (int t = 0; t < TT; ++t) {
        vi += rdlane(zc, t);
        const float si = vi >= 1.0f ? 1.0f : 0.0f;
        vi *= (1.0f - si);
        if (t == lane) sreg = si;
    }
    const unsigned long long mm = __ballot(sreg > 0.5f);
    if (lane == 0) simask[wid] = mm;
}

// ---------------------------------------------------------------------------
// Kernel B: one block per n, 128 threads.
// Phase 1: lane-per-cell square-model chains -> fs[t][c] in LDS.
// Phase 2: wave 0, lane t sums fs[t][:] over C.
// Phase 3: wave 0 runs the per-n scan; g1 reconstructed locally from a
// ballot bitmask (bit-exact, no shuffles on the critical path).
// ---------------------------------------------------------------------------
__global__ __launch_bounds__(128) void kB_pern(
    const unsigned long long* __restrict__ simask, // (N*C)
    const float* __restrict__ w1,  const float* __restrict__ b1,
    const float* __restrict__ w2,  const float* __restrict__ b2,
    const float* __restrict__ sw0, const float* __restrict__ sb0,
    const float* __restrict__ sw1, const float* __restrict__ sb1,
    const float* __restrict__ sw2, const float* __restrict__ sb2,
    float* __restrict__ out)                       // (T,N,1)
{
#pragma clang fp contract(off)
    __shared__ float fsl[TT][CC + 1];
    const int n = blockIdx.x;
    const int tid = threadIdx.x;                   // 0..127 = cell c

    // ---- phase 1: square model per cell ----
    {
        unsigned long long sm = simask[n * CC + tid];
        float W1[10], B1[10], W2[10];
#pragma unroll
        for (int k = 0; k < 10; ++k) { W1[k] = w1[k]; B1[k] = b1[k]; W2[k] = w2[k]; }
        const float B2 = b2[0];
        float f1 = 0.f, v2 = 0.f, fs = 0.f;
        float v1[10], f2[10];
#pragma unroll
        for (int k = 0; k < 10; ++k) { v1[k] = 0.f; f2[k] = 0.f; }

        for (int t = 0; t < TT; ++t) {
            const float si = (float)((int)(sm & 1ull)); sm >>= 1;
            f1 = f1 * 0.5f + si;
            float acc = 0.f;
#pragma unroll
            for (int k = 0; k < 10; ++k) {
                v1[k] += f1 * W1[k] + B1[k];
                const float s1 = v1[k] >= 1.0f ? 1.0f : 0.0f;
                v1[k] *= (1.0f - s1);
                f2[k] = f2[k] * 0.5f + s1;
                acc += f2[k] * W2[k];
            }
            v2 += acc + B2;
            const float s2 = v2 >= 1.0f ? 1.0f : 0.0f;
            v2 *= (1.0f - s2);
            fs = fs * 0.5f + s2;
            fsl[t][tid] = fs;
        }
    }
    __syncthreads();
    if (tid >= 64) return;                         // wave 1 done

    // ---- phase 2: lane tt sums row tt over the 128 cells ----
    float sums;
    {
        float a0 = 0.f, a1 = 0.f, a2 = 0.f, a3 = 0.f;
        const float* row = &fsl[tid][0];
#pragma unroll
        for (int c = 0; c < CC; c += 4) {
            a0 += row[c + 0]; a1 += row[c + 1];
            a2 += row[c + 2]; a3 += row[c + 3];
        }
        sums = (a0 + a1) + (a2 + a3);
    }

    // ---- phase 3: per-n scan. lane = k + 32*h ----
    const int k = tid & 31;
    const int h = tid >> 5;
    const float SW0 = sw0[k], SB0 = sb0[k], SB1 = sb1[k];
    float SW1[16];
#pragma unroll
    for (int j = 0; j < 16; ++j) SW1[j] = sw1[k * 32 + h * 16 + j];
    const float SW2j = (tid < 32) ? sw2[k] : 0.0f;
    const float SB2 = sb2[0];

    float vs = 0.f, q0 = 0.f, q1 = 0.f, g2 = 0.f, q2 = 0.f;
    float g1loc[16];
#pragma unroll
    for (int j = 0; j < 16; ++j) g1loc[j] = 0.f;

    for (int t = 0; t < TT; ++t) {
        const float p = rdlane(sums, t);

        vs += p;
        const float s = vs >= 1.0f ? 1.0f : 0.0f;
        vs *= (1.0f - s);

        q0 += s * SW0 + SB0;
        const float s0 = q0 >= 1.0f ? 1.0f : 0.0f;
        q0 *= (1.0f - s0);

        // s0 bits for k=0..31 live in the low word (upper half mirrors)
        const unsigned m = (unsigned)__ballot(s0 > 0.5f);

        // local reconstruction of g1[h*16+j] — identical FP ops as producer
#pragma unroll
        for (int j = 0; j < 16; ++j)
            g1loc[j] = g1loc[j] * 0.5f + (float)((m >> (h * 16 + j)) & 1u);

        // q1[k] += sum_j sw1[k,j]*g1[j], same order as before
        float a0 = 0.f, a1 = 0.f, a2 = 0.f, a3 = 0.f;
#pragma unroll
        for (int j = 0; j < 16; j += 4) {
            a0 += SW1[j + 0] * g1loc[j + 0];
            a1 += SW1[j + 1] * g1loc[j + 1];
            a2 += SW1[j + 2] * g1loc[j + 2];
            a3 += SW1[j + 3] * g1loc[j + 3];
        }
        float part = (a0 + a1) + (a2 + a3);
        part += __shfl_xor(part, 32);
        q1 += part + SB1;
        const float s1 = q1 >= 1.0f ? 1.0f : 0.0f;
        q1 *= (1.0f - s1);
        g2 = g2 * 0.5f + s1;

        // q2 += sum_j g2[j]*sw2[j]  (NonSpikingIF, pure sink — off critical path)
        float pv = g2 * SW2j;
        pv = wave_reduce63(pv);
        q2 += rdlane(pv, 63) + SB2;

        if (tid == 0) out[t * NN + n] = q2;
    }
}

// ---------------------------------------------------------------------------
extern "C" void kernel_launch(void* const* d_in, const int* in_sizes, int n_in,
                              void* d_out, int out_size, void* d_ws, size_t ws_size,
                              hipStream_t stream)
{
    const float* x   = (const float*)d_in[0];
    const float* w1  = (const float*)d_in[1];
    const float* b1  = (const float*)d_in[2];
    const float* w2  = (const float*)d_in[3];
    const float* b2  = (const float*)d_in[4];
    const float* sw0 = (const float*)d_in[5];
    const float* sb0 = (const float*)d_in[6];
    const float* sw1 = (const float*)d_in[7];
    const float* sb1 = (const float*)d_in[8];
    const float* sw2 = (const float*)d_in[9];
    const float* sb2 = (const float*)d_in[10];
    float* out = (float*)d_out;

    unsigned long long* simask = (unsigned long long*)d_ws;  // 4096 * 8B = 32 KiB

    hipLaunchKernelGGL(k1a_jeffress, dim3((NN * CC) / 4), dim3(256), 0, stream,
                       x, simask);
    hipLaunchKernelGGL(kB_pern, dim3(NN), dim3(128), 0, stream,
                       simask, w1, b1, w2, b2, sw0, sb0, sw1, sb1, sw2, sb2, out);
}

// Round 4
// 49.254 us; speedup vs baseline: 1.2524x; 1.2524x over previous
//
#include <hip/hip_runtime.h>
#include <math.h>

typedef unsigned long long ull;

#define TT 64
#define NN 32
#define CC 128
#define DD 64

// ---------------------------------------------------------------------------
// DPP helpers (VALU-pipe cross-lane) — used in kB2 phase 3 only
// ---------------------------------------------------------------------------
#define DPPADD(x, ctrl, rm)                                                   \
    x += __builtin_bit_cast(float, __builtin_amdgcn_update_dpp(               \
             0, __builtin_bit_cast(int, x), ctrl, rm, 0xf, false))

__device__ __forceinline__ float wave_reduce63(float x) {
    DPPADD(x, 0x111, 0xf);  // row_shr:1
    DPPADD(x, 0x112, 0xf);  // row_shr:2
    DPPADD(x, 0x114, 0xf);  // row_shr:4
    DPPADD(x, 0x118, 0xf);  // row_shr:8
    DPPADD(x, 0x142, 0xa);  // row_bcast:15
    DPPADD(x, 0x143, 0xc);  // row_bcast:31 -> lane63 = total
    return x;
}

__device__ __forceinline__ float rdlane(float x, int l) {
    return __builtin_bit_cast(float,
        __builtin_amdgcn_readlane(__builtin_bit_cast(int, x), l));
}

// ---------------------------------------------------------------------------
// Kernel 1a: one wave per (n,c). lane = jeffress dim d.
// Static-bfe delay lines, Markstein CR division, ballot rows, local zc dot,
// lane-redundant integrator scan -> 64-bit spike mask per cell.
// ---------------------------------------------------------------------------
__global__ __launch_bounds__(256) void k1a_jeffress(
    const float* __restrict__ x,                 // (T,N,2,C)
    ull* __restrict__ simask)                    // (N*C)
{
#pragma clang fp contract(off)
    const int lane = threadIdx.x & 63;
    const int wid  = (blockIdx.x << 2) + (threadIdx.x >> 6);  // n*C + c
    const int n = wid >> 7;
    const int c = wid & 127;

    const float x0 = x[((lane * NN + n) * 2 + 0) * CC + c];
    const float x1 = x[((lane * NN + n) * 2 + 1) * CC + c];
    const ull m0 = __ballot(x0 > 0.5f) << lane;          // bit t = x0[t-lane]
    const ull m1 = __ballot(x1 > 0.5f) << (63 - lane);   // bit t = x1[t-63+lane]
    const unsigned m0lo = (unsigned)m0, m0hi = (unsigned)(m0 >> 32);
    const unsigned m1lo = (unsigned)m1, m1hi = (unsigned)(m1 >> 32);

    int ad = lane - (DD / 2);
    if (ad < 0) ad = -ad;
    if (ad == 0) ad = 1;                         // center clamp
    const float kint = 1.0f / (1.0f - expf(-(float)ad * 0.5f));

    const float R = 0.05f;                       // RN(1/20)
    float vj = 0.f;
    unsigned rlo = 0u, rhi = 0u;                 // spike-matrix row t (on lane t)
#pragma unroll
    for (int t = 0; t < TT; ++t) {
        const unsigned b0 = (t < 32) ? ((m0lo >> t) & 1u) : ((m0hi >> (t - 32)) & 1u);
        const unsigned b1 = (t < 32) ? ((m1lo >> t) & 1u) : ((m1hi >> (t - 32)) & 1u);
        const float u = (float)(b0 + b1);

        // vj += (u - vj)/20, division via Markstein CR sequence
        const float num = u - vj;
        const float q0  = num * R;
        const float q   = fmaf(fmaf(-20.0f, q0, num), R, q0);
        vj = vj + q;

        const bool sp = vj >= 1.0f;
        const ull m = __ballot(sp);
        vj = sp ? 0.0f : vj;
        if (t == lane) { rlo = (unsigned)m; rhi = (unsigned)(m >> 32); }
    }

    // zc[t] on lane t: dot(spike row, kint). fma exact-equivalent to mul+add
    // because each product is exactly 0 or kd.
    float zc = 0.f;
#pragma unroll
    for (int d = 0; d < 64; ++d) {
        const float kd = rdlane(kint, d);
        const unsigned bit = (d < 32) ? ((rlo >> d) & 1u) : ((rhi >> (d - 32)) & 1u);
        zc = fmaf((float)bit, kd, zc);
    }

    // lane-redundant serial integrator IF
    float vi = 0.f, sreg = 0.f;
#pragma unroll
    for (int t = 0; t < TT; ++t) {
        vi += rdlane(zc, t);
        const bool sp = vi >= 1.0f;
        const float siF = sp ? 1.0f : 0.0f;
        vi = sp ? 0.0f : vi;
        if (t == lane) sreg = siF;
    }
    const ull mm = __ballot(sreg > 0.5f);
    if (lane == 0) simask[wid] = mm;
}

// ---------------------------------------------------------------------------
// Kernel B1: square model, 16 lanes per cell (k-units lane-parallel).
// 4096 cells, 256 threads/block (16 cells) -> 256 blocks, 1 wave/SIMD.
// Emits fs to fsbuf[(n*C+c)*T + t].
// ---------------------------------------------------------------------------
__global__ __launch_bounds__(256) void kB1_square(
    const ull* __restrict__ simask,              // (N*C)
    const float* __restrict__ w1,  const float* __restrict__ b1,
    const float* __restrict__ w2,  const float* __restrict__ b2,
    float* __restrict__ fsbuf)                   // (N*C, T)
{
#pragma clang fp contract(off)
    __shared__ float fsl[16][TT + 1];
    const int tid = threadIdx.x;
    const int g   = tid & 15;                    // lane-in-group = k (0..9 live)
    const int cib = tid >> 4;                    // cell-in-block 0..15
    const int cell = (blockIdx.x << 4) + cib;    // n*C + c

    const ull mm = simask[cell];
    const unsigned mlo = (unsigned)mm, mhi = (unsigned)(mm >> 32);

    const int k = (g < 10) ? g : 0;
    const float W1k = w1[k], B1k = b1[k];
    const float W2k = (g < 10) ? w2[k] : 0.0f;   // dead lanes contribute 0
    const float B2  = b2[0];

    float f1 = 0.f, v1 = 0.f, f2 = 0.f, v2 = 0.f, fs = 0.f;

#pragma unroll
    for (int t = 0; t < TT; ++t) {
        const float si = (float)((t < 32) ? ((mlo >> t) & 1u)
                                          : ((mhi >> (t - 32)) & 1u));
        f1 = f1 * 0.5f + si;

        v1 = v1 + (f1 * W1k + B1k);              // same assoc as rounds 2-3
        const bool s1b = v1 >= 1.0f;
        const float s1 = s1b ? 1.0f : 0.0f;
        v1 = s1b ? 0.0f : v1;

        f2 = f2 * 0.5f + s1;
        float acc = f2 * W2k;
        // 10-term sum via xor-butterfly within the 16-lane group
        acc += __shfl_xor(acc, 1);
        acc += __shfl_xor(acc, 2);
        acc += __shfl_xor(acc, 4);
        acc += __shfl_xor(acc, 8);

        v2 = v2 + (acc + B2);
        const bool s2b = v2 >= 1.0f;
        const float s2 = s2b ? 1.0f : 0.0f;
        v2 = s2b ? 0.0f : v2;

        fs = fs * 0.5f + s2;
        fsl[cib][t] = fs;                        // all 16 lanes, same value
    }
    __syncthreads();

    // coalesced dump: fsbuf[cell*64 + t] for the block's 16 cells
    float* dst = fsbuf + (blockIdx.x << 10);
#pragma unroll
    for (int i = tid; i < 16 * TT; i += 256)
        dst[i] = fsl[i >> 6][i & 63];
}

// ---------------------------------------------------------------------------
// Kernel B2: one wave per n. Phase 2 (sum over C) + phase 3 (per-n scan),
// bit-identical to round 3's validated code.
// ---------------------------------------------------------------------------
__global__ __launch_bounds__(64) void kB2_pern(
    const float* __restrict__ fsbuf,             // (N*C, T)
    const float* __restrict__ sw0, const float* __restrict__ sb0,
    const float* __restrict__ sw1, const float* __restrict__ sb1,
    const float* __restrict__ sw2, const float* __restrict__ sb2,
    float* __restrict__ out)                     // (T,N,1)
{
#pragma clang fp contract(off)
    const int n = blockIdx.x;
    const int lane = threadIdx.x;                // 0..63 ; phase-2 t = lane

    // phase 2: lane t sums fs[t] over the 128 cells of this n (same order
    // as round 3: interleaved 4-accumulator, c ascending)
    const float* base = fsbuf + n * (CC * TT);
    float a0 = 0.f, a1 = 0.f, a2 = 0.f, a3 = 0.f;
#pragma unroll
    for (int c = 0; c < CC; c += 4) {
        a0 += base[(c + 0) * TT + lane];
        a1 += base[(c + 1) * TT + lane];
        a2 += base[(c + 2) * TT + lane];
        a3 += base[(c + 3) * TT + lane];
    }
    const float sums = (a0 + a1) + (a2 + a3);

    // phase 3: per-n scan. lane = k + 32*h
    const int k = lane & 31;
    const int h = lane >> 5;
    const float SW0 = sw0[k], SB0 = sb0[k], SB1 = sb1[k];
    float SW1[16];
#pragma unroll
    for (int j = 0; j < 16; ++j) SW1[j] = sw1[k * 32 + h * 16 + j];
    const float SW2j = (lane < 32) ? sw2[k] : 0.0f;
    const float SB2 = sb2[0];

    float vs = 0.f, q0 = 0.f, q1 = 0.f, g2 = 0.f, q2 = 0.f;
    float g1loc[16];
#pragma unroll
    for (int j = 0; j < 16; ++j) g1loc[j] = 0.f;

    for (int t = 0; t < TT; ++t) {
        const float p = rdlane(sums, t);

        vs += p;
        const float s = vs >= 1.0f ? 1.0f : 0.0f;
        vs *= (1.0f - s);

        q0 += s * SW0 + SB0;
        const float s0 = q0 >= 1.0f ? 1.0f : 0.0f;
        q0 *= (1.0f - s0);

        const unsigned m = (unsigned)__ballot(s0 > 0.5f);

#pragma unroll
        for (int j = 0; j < 16; ++j)
            g1loc[j] = g1loc[j] * 0.5f + (float)((m >> (h * 16 + j)) & 1u);

        float b0 = 0.f, b1 = 0.f, b2a = 0.f, b3 = 0.f;
#pragma unroll
        for (int j = 0; j < 16; j += 4) {
            b0 += SW1[j + 0] * g1loc[j + 0];
            b1 += SW1[j + 1] * g1loc[j + 1];
            b2a += SW1[j + 2] * g1loc[j + 2];
            b3 += SW1[j + 3] * g1loc[j + 3];
        }
        float part = (b0 + b1) + (b2a + b3);
        part += __shfl_xor(part, 32);
        q1 += part + SB1;
        const float s1 = q1 >= 1.0f ? 1.0f : 0.0f;
        q1 *= (1.0f - s1);
        g2 = g2 * 0.5f + s1;

        float pv = g2 * SW2j;
        pv = wave_reduce63(pv);
        q2 += rdlane(pv, 63) + SB2;

        if (lane == 0) out[t * NN + n] = q2;
    }
}

// ---------------------------------------------------------------------------
extern "C" void kernel_launch(void* const* d_in, const int* in_sizes, int n_in,
                              void* d_out, int out_size, void* d_ws, size_t ws_size,
                              hipStream_t stream)
{
    const float* x   = (const float*)d_in[0];
    const float* w1  = (const float*)d_in[1];
    const float* b1  = (const float*)d_in[2];
    const float* w2  = (const float*)d_in[3];
    const float* b2  = (const float*)d_in[4];
    const float* sw0 = (const float*)d_in[5];
    const float* sb0 = (const float*)d_in[6];
    const float* sw1 = (const float*)d_in[7];
    const float* sb1 = (const float*)d_in[8];
    const float* sw2 = (const float*)d_in[9];
    const float* sb2 = (const float*)d_in[10];
    float* out = (float*)d_out;

    ull*   simask = (ull*)d_ws;                       // 4096 * 8 B
    float* fsbuf  = (float*)((char*)d_ws + (1 << 20)); // 4096*64*4 B = 1 MiB

    hipLaunchKernelGGL(k1a_jeffress, dim3((NN * CC) / 4), dim3(256), 0, stream,
                       x, simask);
    hipLaunchKernelGGL(kB1_square, dim3((NN * CC) / 16), dim3(256), 0, stream,
                       simask, w1, b1, w2, b2, fsbuf);
    hipLaunchKernelGGL(kB2_pern, dim3(NN), dim3(64), 0, stream,
                       fsbuf, sw0, sb0, sw1, sb1, sw2, sb2, out);
}